// Round 15
// baseline (342.397 us; speedup 1.0000x reference)
//
#include <hip/hip_runtime.h>

#define T_TOK 4096
#define D_DIM 1024
#define F_DIM 2048
#define E_NUM 8
#define MAX_TILES 136
#define TZ 16   // leading y-slices of gemm1 grid doing w2 transpose

typedef __attribute__((ext_vector_type(8))) short bf16x8;
typedef __attribute__((ext_vector_type(4))) float f32x4;
typedef unsigned short us;

__device__ __forceinline__ us f2bf(float f) {
  unsigned u = __builtin_bit_cast(unsigned, f);
  unsigned r = 0x7FFFu + ((u >> 16) & 1u);
  return (us)((u + r) >> 16);
}

__device__ __forceinline__ void gload16(const us* g, us* l) {
  __builtin_amdgcn_global_load_lds(
      (const __attribute__((address_space(1))) unsigned int*)g,
      (__attribute__((address_space(3))) unsigned int*)l, 16, 0, 0);
}

__device__ __forceinline__ f32x4 mfma16(bf16x8 a, bf16x8 b, f32x4 c) {
  return __builtin_amdgcn_mfma_f32_16x16x32_bf16(a, b, c, 0, 0, 0);
}

// ---------------- prep: transpose+convert w1,w3 (z<16)  |  logits+x->bf16 (z>=16) --------
__global__ __launch_bounds__(256) void prep_kernel(
    const float* __restrict__ w1, const float* __restrict__ w3,
    us* __restrict__ W1t, us* __restrict__ W3t,
    const float* __restrict__ x, const float* __restrict__ gw,
    int* __restrict__ route_e, float2* __restrict__ route_w,
    us* __restrict__ Xb) {
  int z = blockIdx.z;
  int tid = threadIdx.x;

  if (z < 16) {
    // ---- weight transpose+convert: [D][F] -> [F][D] ----
    __shared__ float tile[64][65];
    int which = z >> 3, e = z & 7;
    const float* src = (which == 0 ? w1 : w3);
    us* dst = (which == 0 ? W1t : W3t);
    src += (size_t)e * D_DIM * F_DIM; dst += (size_t)e * D_DIM * F_DIM;
    int bid = blockIdx.y * gridDim.x + blockIdx.x;
    int nbx = F_DIM / 64;
    int i0 = (bid / nbx) * 64, j0 = (bid % nbx) * 64;
    int lr = tid >> 4, lc = (tid & 15) * 4;
    #pragma unroll
    for (int p = 0; p < 4; p++) {
      int row = p * 16 + lr;
      float4 v = *(const float4*)&src[(size_t)(i0 + row) * F_DIM + j0 + lc];
      tile[row][lc + 0] = v.x; tile[row][lc + 1] = v.y;
      tile[row][lc + 2] = v.z; tile[row][lc + 3] = v.w;
    }
    __syncthreads();
    #pragma unroll
    for (int p = 0; p < 4; p++) {
      int orow = p * 16 + lr;
      us b0 = f2bf(tile[lc + 0][orow]);
      us b1 = f2bf(tile[lc + 1][orow]);
      us b2 = f2bf(tile[lc + 2][orow]);
      us b3 = f2bf(tile[lc + 3][orow]);
      uint2 o;
      o.x = b0 | ((unsigned)b1 << 16);
      o.y = b2 | ((unsigned)b3 << 16);
      *(uint2*)&dst[(size_t)(j0 + orow) * D_DIM + i0 + lc] = o;
    }
  } else {
    // ---- router logits (+ fused x->bf16), 1 wave per token ----
    int bid = (z - 16) * 512 + blockIdx.y * gridDim.x + blockIdx.x;  // 0..1023
    int lane = tid & 63;
    int t = bid * 4 + (tid >> 6);
    float acc[E_NUM];
    #pragma unroll
    for (int e = 0; e < E_NUM; e++) acc[e] = 0.f;
    const float* xr = x + (size_t)t * D_DIM;
    us* xbr = Xb + (size_t)t * D_DIM;
    #pragma unroll
    for (int j = 0; j < D_DIM / 64; j++) {
      int d = lane + 64 * j;
      float xv = xr[d];
      xbr[d] = f2bf(xv);
      const float4* g = reinterpret_cast<const float4*>(gw + (size_t)d * E_NUM);
      float4 g0 = g[0], g1 = g[1];
      acc[0] += xv * g0.x; acc[1] += xv * g0.y; acc[2] += xv * g0.z; acc[3] += xv * g0.w;
      acc[4] += xv * g1.x; acc[5] += xv * g1.y; acc[6] += xv * g1.z; acc[7] += xv * g1.w;
    }
    #pragma unroll
    for (int e = 0; e < E_NUM; e++) {
      #pragma unroll
      for (int off = 32; off > 0; off >>= 1) acc[e] += __shfl_xor(acc[e], off);
    }
    if (lane == 0) {
      int e1 = 0; float l1 = acc[0];
      #pragma unroll
      for (int e = 1; e < E_NUM; e++) { if (acc[e] > l1) { l1 = acc[e]; e1 = e; } }
      int e2 = -1; float l2 = -1e30f;
      #pragma unroll
      for (int e = 0; e < E_NUM; e++) { if (e != e1 && acc[e] > l2) { l2 = acc[e]; e2 = e; } }
      float wa = 1.f / (1.f + expf(l2 - l1));
      float wb = 1.f / (1.f + expf(l1 - l2));
      route_e[t] = e1 | (e2 << 8);
      route_w[t] = make_float2(wa, wb);
    }
  }
}

// ---------------- scatter: deterministic prefix-sum compaction + tiles, 1 block ----------
__global__ __launch_bounds__(1024) void scatter_kernel(
    const int* __restrict__ route_e, const float2* __restrict__ route_w,
    int* __restrict__ counts, int4* __restrict__ tiles,
    int* __restrict__ list, float* __restrict__ wts) {
  int tid = threadIdx.x;
  int lane = tid & 63, wv = tid >> 6;
  __shared__ int wave_tot[16][E_NUM];
  __shared__ int wave_base[16][E_NUM];
  __shared__ int tot_s[E_NUM];

  int e_loc[8]; float w_loc[8];
  #pragma unroll
  for (int j = 0; j < 4; j++) {
    int t = tid * 4 + j;
    int re = route_e[t];
    float2 rw = route_w[t];
    e_loc[2 * j]     = re & 0xff; w_loc[2 * j]     = rw.x;
    e_loc[2 * j + 1] = re >> 8;   w_loc[2 * j + 1] = rw.y;
  }
  int c[E_NUM], pre[E_NUM];
  #pragma unroll
  for (int e = 0; e < E_NUM; e++) {
    int s = 0;
    #pragma unroll
    for (int j = 0; j < 8; j++) s += (e_loc[j] == e) ? 1 : 0;
    c[e] = s;
  }
  #pragma unroll
  for (int e = 0; e < E_NUM; e++) {
    int v = c[e];
    #pragma unroll
    for (int off = 1; off < 64; off <<= 1) {
      int u = __shfl_up(v, off);
      if (lane >= off) v += u;
    }
    pre[e] = v - c[e];
    if (lane == 63) wave_tot[wv][e] = v;
  }
  __syncthreads();
  if (tid < E_NUM) {
    int s = 0;
    for (int w = 0; w < 16; w++) { wave_base[w][tid] = s; s += wave_tot[w][tid]; }
    tot_s[tid] = s;
    counts[tid] = s;
  }
  __syncthreads();
  #pragma unroll
  for (int j = 0; j < 8; j++) {
    int e = e_loc[j];
    int off = 0;
    #pragma unroll
    for (int jj = 0; jj < 8; jj++)
      if (jj < j) off += (e_loc[jj] == e) ? 1 : 0;
    int basee = 0, pree = 0;
    #pragma unroll
    for (int ee = 0; ee < E_NUM; ee++)
      if (e == ee) { basee = wave_base[wv][ee]; pree = pre[ee]; }
    int pos = basee + pree + off;
    int t = tid * 4 + (j >> 1);
    list[e * T_TOK + pos] = t * 2 + (j & 1);
    wts[e * T_TOK + pos]  = w_loc[j];
  }
  // tile descriptors (64-row granularity)
  if (tid < MAX_TILES) {
    int4 tt; tt.x = -1; tt.y = 0; tt.z = 0; tt.w = 0;
    int s = 0;
    #pragma unroll
    for (int e = 0; e < E_NUM; e++) {
      int ntl = (tot_s[e] + 63) >> 6;
      if (tid >= s && tid < s + ntl) { tt.x = e; tt.y = (tid - s) * 64; tt.z = tot_s[e]; }
      s += ntl;
    }
    tiles[tid] = tt;
  }
}

// ---------------- GEMM1 (+ fused w2 transpose in leading y-slices) ----------------
// y < TZ: transpose w2 [F][D]->[D][F].  y >= TZ: 64x64 dual GEMM, A direct-from-global.
__global__ __launch_bounds__(256, 4) void gemm1_kernel(
    const us* __restrict__ Xb,   // [T][D] bf16
    const us* __restrict__ W1t,  // [E][F][D] bf16
    const us* __restrict__ W3t,  // [E][F][D] bf16
    const int4* __restrict__ tiles, const int* __restrict__ list,
    us* __restrict__ H,          // [T*2][F] bf16
    const float* __restrict__ w2, us* __restrict__ W2t) {
  __shared__ __align__(16) us smem[64 * 65 * 2];   // 16.64 KB, aliased by both paths
  __shared__ int rid_s[64];
  int tid = threadIdx.x;

  if (blockIdx.y < TZ) {
    // ---- w2 transpose+convert path ----
    float (*tile)[65] = (float(*)[65])smem;        // 16.64 KB
    int slot = blockIdx.y * 32 + blockIdx.x;       // 0..511: within-expert tile id
    int i0 = (slot >> 4) * 64;                     // F-dim (32 tiles)
    int j0 = (slot & 15) * 64;                     // D-dim (16 tiles)
    int lr = tid >> 4, lc = (tid & 15) * 4;
    #pragma unroll 1
    for (int e = 0; e < E_NUM; e++) {
      const float* src = w2 + (size_t)e * F_DIM * D_DIM;
      us* dst = W2t + (size_t)e * F_DIM * D_DIM;
      #pragma unroll
      for (int p = 0; p < 4; p++) {
        int row = p * 16 + lr;
        float4 v = *(const float4*)&src[(size_t)(i0 + row) * D_DIM + j0 + lc];
        tile[row][lc + 0] = v.x; tile[row][lc + 1] = v.y;
        tile[row][lc + 2] = v.z; tile[row][lc + 3] = v.w;
      }
      __syncthreads();
      #pragma unroll
      for (int p = 0; p < 4; p++) {
        int orow = p * 16 + lr;                    // D-index
        us b0 = f2bf(tile[lc + 0][orow]);
        us b1 = f2bf(tile[lc + 1][orow]);
        us b2 = f2bf(tile[lc + 2][orow]);
        us b3 = f2bf(tile[lc + 3][orow]);
        uint2 o;
        o.x = b0 | ((unsigned)b1 << 16);
        o.y = b2 | ((unsigned)b3 << 16);
        *(uint2*)&dst[(size_t)(j0 + orow) * F_DIM + i0 + lc] = o;
      }
      __syncthreads();
    }
    return;
  }

  // ---- GEMM path: B1/B3 staged in LDS, A fragments direct from global (L2/L3) ----
  us* B1s = smem;
  us* B3s = smem + 4096;

  int4 td = tiles[blockIdx.y - TZ];
  int e = td.x;
  if (e < 0) return;
  int base = td.y, cnt = td.z;
  int nt = blockIdx.x;          // 0..31 over F/64

  if (tid < 64) {
    int r = base + tid; if (r > cnt - 1) r = cnt - 1;
    rid_s[tid] = list[e * T_TOK + r];
  }
  __syncthreads();

  int lane = tid & 63, wid = tid >> 6;       // wid 0..3
  int sr = lane >> 3;                        // 0..7
  int sg = (lane & 7) ^ sr;                  // pre-swizzled source granule
  const us *b1_src[2], *b3_src[2];
  #pragma unroll
  for (int t = 0; t < 2; t++) {
    size_t row = (size_t)e * F_DIM + nt * 64 + wid * 16 + t * 8 + sr;
    b1_src[t] = W1t + row * D_DIM + sg * 8;
    b3_src[t] = W3t + row * D_DIM + sg * 8;
  }

  int wm = (wid >> 1) * 32, wn = (wid & 1) * 32;
  int frow = lane & 15;
  int fk = lane >> 4;

  // per-lane A pointers, loop-invariant: fragment (mf,kc), row=rid_s[wm+mf*16+frow]
  const us* a_ptr[2][2];
  #pragma unroll
  for (int mf = 0; mf < 2; mf++) {
    int rid = rid_s[wm + mf * 16 + frow] >> 1;
    #pragma unroll
    for (int kc = 0; kc < 2; kc++)
      a_ptr[mf][kc] = Xb + (size_t)rid * D_DIM + (kc * 4 + fk) * 8;
  }

  unsigned offB[2][2];
  #pragma unroll
  for (int nf = 0; nf < 2; nf++)
    #pragma unroll
    for (int kc = 0; kc < 2; kc++) {
      int n = wn + nf * 16 + frow, gk = kc * 4 + fk;
      offB[nf][kc] = n * 64 + ((gk ^ (n & 7)) * 8);
    }

  f32x4 acc1[2][2], acc3[2][2];
  #pragma unroll
  for (int mf = 0; mf < 2; mf++)
    #pragma unroll
    for (int nf = 0; nf < 2; nf++) {
      f32x4 z = {0.f, 0.f, 0.f, 0.f};
      acc1[mf][nf] = z; acc3[mf][nf] = z;
    }

  #pragma unroll 1
  for (int k0 = 0; k0 < D_DIM; k0 += 64) {
    // A fragments: global -> VGPR (issue first; latency hides under B-stage + barrier)
    bf16x8 a[2][2];
    #pragma unroll
    for (int mf = 0; mf < 2; mf++)
      #pragma unroll
      for (int kc = 0; kc < 2; kc++)
        a[mf][kc] = *(const bf16x8*)(a_ptr[mf][kc] + k0);
    // B: global -> LDS staging
    #pragma unroll
    for (int t = 0; t < 2; t++) {
      gload16(b1_src[t] + k0, &B1s[(wid * 16 + t * 8) * 64]);
      gload16(b3_src[t] + k0, &B3s[(wid * 16 + t * 8) * 64]);
    }
    __syncthreads();
    #pragma unroll
    for (int kc = 0; kc < 2; kc++) {
      bf16x8 b1[2], b3[2];
      #pragma unroll
      for (int nf = 0; nf < 2; nf++) {
        b1[nf] = *(const bf16x8*)&B1s[offB[nf][kc]];
        b3[nf] = *(const bf16x8*)&B3s[offB[nf][kc]];
      }
      #pragma unroll
      for (int mf = 0; mf < 2; mf++)
        #pragma unroll
        for (int nf = 0; nf < 2; nf++) {
          acc1[mf][nf] = mfma16(a[mf][kc], b1[nf], acc1[mf][nf]);
          acc3[mf][nf] = mfma16(a[mf][kc], b3[nf], acc3[mf][nf]);
        }
    }
    __syncthreads();
  }

  #pragma unroll
  for (int mf = 0; mf < 2; mf++) {
    #pragma unroll
    for (int i = 0; i < 4; i++) {
      int m = wm + mf * 16 + fk * 4 + i;
      if (base + m < cnt) {
        int rid = rid_s[m];
        us* hrow = H + (size_t)rid * F_DIM + nt * 64 + wn;
        #pragma unroll
        for (int nf = 0; nf < 2; nf++) {
          float z = acc1[mf][nf][i];
          float u = acc3[mf][nf][i];
          hrow[nf * 16 + frow] = f2bf((z / (1.f + expf(-z))) * u);
        }
      }
    }
  }
}

// ---------------- GEMM2: out += (H @ w2) * weight, 64x128, A direct-from-global ----------
__global__ __launch_bounds__(256, 4) void gemm2_kernel(
    const us* __restrict__ H,    // [T*2][F] bf16
    const us* __restrict__ W2t,  // [E][D][F] bf16
    const int4* __restrict__ tiles, const int* __restrict__ list,
    const float* __restrict__ wts,
    float* __restrict__ out) {   // [T][D] fp32 (pre-zeroed)
  __shared__ us Bs[128 * 64];    // 16 KB
  __shared__ int rid_s[64];
  __shared__ float wt_s[64];

  int4 td = tiles[blockIdx.y];
  int e = td.x;
  if (e < 0) return;
  int base = td.y, cnt = td.z;
  int nt = blockIdx.x;   // 0..7 over D/128
  int tid = threadIdx.x;

  if (tid < 64) {
    int r = base + tid; if (r > cnt - 1) r = cnt - 1;
    rid_s[tid] = list[e * T_TOK + r];
    wt_s[tid] = wts[e * T_TOK + r];
  }
  __syncthreads();

  int lane = tid & 63, wid = tid >> 6;
  int sr = lane >> 3;
  int sg = (lane & 7) ^ sr;
  const us* b_src[4];
  #pragma unroll
  for (int t = 0; t < 4; t++)
    b_src[t] = W2t + ((size_t)e * D_DIM + nt * 128 + wid * 32 + t * 8 + sr) * F_DIM + sg * 8;

  int wm = (wid >> 1) * 32, wn = (wid & 1) * 64;
  int frow = lane & 15;
  int fk = lane >> 4;

  // per-lane A pointers (H rows), loop-invariant
  const us* a_ptr[2][2];
  #pragma unroll
  for (int mf = 0; mf < 2; mf++) {
    int rid = rid_s[wm + mf * 16 + frow];
    #pragma unroll
    for (int kc = 0; kc < 2; kc++)
      a_ptr[mf][kc] = H + (size_t)rid * F_DIM + (kc * 4 + fk) * 8;
  }

  unsigned offB[4][2];
  #pragma unroll
  for (int nf = 0; nf < 4; nf++)
    #pragma unroll
    for (int kc = 0; kc < 2; kc++) {
      int n = wn + nf * 16 + frow, gk = kc * 4 + fk;
      offB[nf][kc] = n * 64 + ((gk ^ (n & 7)) * 8);
    }

  f32x4 acc[2][4];
  #pragma unroll
  for (int mf = 0; mf < 2; mf++)
    #pragma unroll
    for (int nf = 0; nf < 4; nf++) {
      f32x4 z = {0.f, 0.f, 0.f, 0.f};
      acc[mf][nf] = z;
    }

  #pragma unroll 1
  for (int k0 = 0; k0 < F_DIM; k0 += 64) {
    bf16x8 a[2][2];
    #pragma unroll
    for (int mf = 0; mf < 2; mf++)
      #pragma unroll
      for (int kc = 0; kc < 2; kc++)
        a[mf][kc] = *(const bf16x8*)(a_ptr[mf][kc] + k0);
    #pragma unroll
    for (int t = 0; t < 4; t++)
      gload16(b_src[t] + k0, &Bs[(wid * 32 + t * 8) * 64]);
    __syncthreads();
    #pragma unroll
    for (int kc = 0; kc < 2; kc++) {
      bf16x8 b[4];
      #pragma unroll
      for (int nf = 0; nf < 4; nf++) b[nf] = *(const bf16x8*)&Bs[offB[nf][kc]];
      #pragma unroll
      for (int mf = 0; mf < 2; mf++)
        #pragma unroll
        for (int nf = 0; nf < 4; nf++)
          acc[mf][nf] = mfma16(a[mf][kc], b[nf], acc[mf][nf]);
    }
    __syncthreads();
  }

  #pragma unroll
  for (int mf = 0; mf < 2; mf++) {
    #pragma unroll
    for (int i = 0; i < 4; i++) {
      int m = wm + mf * 16 + fk * 4 + i;
      if (base + m < cnt) {
        int tok = rid_s[m] >> 1;
        float w = wt_s[m];
        float* orow = out + (size_t)tok * D_DIM + nt * 128 + wn;
        #pragma unroll
        for (int nf = 0; nf < 4; nf++)
          atomicAdd(&orow[nf * 16 + frow], acc[mf][nf][i] * w);
      }
    }
  }
}

extern "C" void kernel_launch(void* const* d_in, const int* in_sizes, int n_in,
                              void* d_out, int out_size, void* d_ws, size_t ws_size,
                              hipStream_t stream) {
  const float* x  = (const float*)d_in[0];
  const float* gw = (const float*)d_in[1];
  const float* w1 = (const float*)d_in[2];
  const float* w2 = (const float*)d_in[3];
  const float* w3 = (const float*)d_in[4];
  float* out = (float*)d_out;

  char* ws = (char*)d_ws;
  const size_t LISTB = (size_t)E_NUM * T_TOK * 4;
  size_t o_counts  = 0;
  size_t o_tiles   = 256;                                   // int4[136]
  size_t o_route_e = 4096;
  size_t o_route_w = o_route_e + (size_t)T_TOK * 4;
  size_t o_list    = o_route_w + (size_t)T_TOK * 8;
  size_t o_wts     = o_list + LISTB;
  size_t o_Xb      = o_wts + LISTB;
  size_t o_W1t     = o_Xb + (size_t)T_TOK * D_DIM * 2;
  size_t wt_sz     = (size_t)E_NUM * F_DIM * D_DIM * 2;
  size_t o_W3t     = o_W1t + wt_sz;
  size_t o_W2t     = o_W3t + wt_sz;
  size_t o_H       = o_W2t + wt_sz;

  int* counts    = (int*)(ws + o_counts);
  int4* tiles    = (int4*)(ws + o_tiles);
  int* route_e   = (int*)(ws + o_route_e);
  float2* route_w = (float2*)(ws + o_route_w);
  int* list      = (int*)(ws + o_list);
  float* wts     = (float*)(ws + o_wts);
  us* Xb  = (us*)(ws + o_Xb);
  us* W1t = (us*)(ws + o_W1t);
  us* W3t = (us*)(ws + o_W3t);
  us* W2t = (us*)(ws + o_W2t);
  us* H   = (us*)(ws + o_H);

  hipMemsetAsync(out, 0, (size_t)out_size * 4, stream);

  // z<16: w1/w3 transpose; z=16..17: router logits (co-resident)
  prep_kernel<<<dim3(32, 16, 18), 256, 0, stream>>>(
      w1, w3, W1t, W3t, x, gw, route_e, route_w, Xb);

  scatter_kernel<<<dim3(1), 1024, 0, stream>>>(route_e, route_w, counts,
                                               tiles, list, wts);

  // y<TZ: w2 transpose (hidden under gemm compute); y>=TZ: gemm tiles
  gemm1_kernel<<<dim3(F_DIM / 64, TZ + MAX_TILES), 256, 0, stream>>>(
      Xb, W1t, W3t, tiles, list, H, w2, W2t);
  gemm2_kernel<<<dim3(D_DIM / 128, MAX_TILES), 256, 0, stream>>>(
      H, W2t, tiles, list, wts, out);
}

// Round 16
// 233.033 us; speedup vs baseline: 1.4693x; 1.4693x over previous
//
#include <hip/hip_runtime.h>

#define T_TOK 4096
#define D_DIM 1024
#define F_DIM 2048
#define E_NUM 8
#define MAX_TILES 136
#define TZ 16   // leading y-slices of gemm1 grid doing w2 transpose

typedef __attribute__((ext_vector_type(8))) short bf16x8;
typedef __attribute__((ext_vector_type(4))) float f32x4;
typedef unsigned short us;

__device__ __forceinline__ us f2bf(float f) {
  unsigned u = __builtin_bit_cast(unsigned, f);
  unsigned r = 0x7FFFu + ((u >> 16) & 1u);
  return (us)((u + r) >> 16);
}

__device__ __forceinline__ void gload16(const us* g, us* l) {
  __builtin_amdgcn_global_load_lds(
      (const __attribute__((address_space(1))) unsigned int*)g,
      (__attribute__((address_space(3))) unsigned int*)l, 16, 0, 0);
}

__device__ __forceinline__ f32x4 mfma16(bf16x8 a, bf16x8 b, f32x4 c) {
  return __builtin_amdgcn_mfma_f32_16x16x32_bf16(a, b, c, 0, 0, 0);
}

// ---------------- prep: transpose+convert w1,w3 (z<16)  |  logits+x->bf16 (z>=16) --------
__global__ __launch_bounds__(256) void prep_kernel(
    const float* __restrict__ w1, const float* __restrict__ w3,
    us* __restrict__ W1t, us* __restrict__ W3t,
    const float* __restrict__ x, const float* __restrict__ gw,
    int* __restrict__ route_e, float2* __restrict__ route_w,
    us* __restrict__ Xb) {
  int z = blockIdx.z;
  int tid = threadIdx.x;

  if (z < 16) {
    // ---- weight transpose+convert: [D][F] -> [F][D] ----
    __shared__ float tile[64][65];
    int which = z >> 3, e = z & 7;
    const float* src = (which == 0 ? w1 : w3);
    us* dst = (which == 0 ? W1t : W3t);
    src += (size_t)e * D_DIM * F_DIM; dst += (size_t)e * D_DIM * F_DIM;
    int bid = blockIdx.y * gridDim.x + blockIdx.x;
    int nbx = F_DIM / 64;
    int i0 = (bid / nbx) * 64, j0 = (bid % nbx) * 64;
    int lr = tid >> 4, lc = (tid & 15) * 4;
    #pragma unroll
    for (int p = 0; p < 4; p++) {
      int row = p * 16 + lr;
      float4 v = *(const float4*)&src[(size_t)(i0 + row) * F_DIM + j0 + lc];
      tile[row][lc + 0] = v.x; tile[row][lc + 1] = v.y;
      tile[row][lc + 2] = v.z; tile[row][lc + 3] = v.w;
    }
    __syncthreads();
    #pragma unroll
    for (int p = 0; p < 4; p++) {
      int orow = p * 16 + lr;
      us b0 = f2bf(tile[lc + 0][orow]);
      us b1 = f2bf(tile[lc + 1][orow]);
      us b2 = f2bf(tile[lc + 2][orow]);
      us b3 = f2bf(tile[lc + 3][orow]);
      uint2 o;
      o.x = b0 | ((unsigned)b1 << 16);
      o.y = b2 | ((unsigned)b3 << 16);
      *(uint2*)&dst[(size_t)(j0 + orow) * D_DIM + i0 + lc] = o;
    }
  } else {
    // ---- router logits (+ fused x->bf16), 1 wave per token ----
    int bid = (z - 16) * 512 + blockIdx.y * gridDim.x + blockIdx.x;  // 0..1023
    int lane = tid & 63;
    int t = bid * 4 + (tid >> 6);
    float acc[E_NUM];
    #pragma unroll
    for (int e = 0; e < E_NUM; e++) acc[e] = 0.f;
    const float* xr = x + (size_t)t * D_DIM;
    us* xbr = Xb + (size_t)t * D_DIM;
    #pragma unroll
    for (int j = 0; j < D_DIM / 64; j++) {
      int d = lane + 64 * j;
      float xv = xr[d];
      xbr[d] = f2bf(xv);
      const float4* g = reinterpret_cast<const float4*>(gw + (size_t)d * E_NUM);
      float4 g0 = g[0], g1 = g[1];
      acc[0] += xv * g0.x; acc[1] += xv * g0.y; acc[2] += xv * g0.z; acc[3] += xv * g0.w;
      acc[4] += xv * g1.x; acc[5] += xv * g1.y; acc[6] += xv * g1.z; acc[7] += xv * g1.w;
    }
    #pragma unroll
    for (int e = 0; e < E_NUM; e++) {
      #pragma unroll
      for (int off = 32; off > 0; off >>= 1) acc[e] += __shfl_xor(acc[e], off);
    }
    if (lane == 0) {
      int e1 = 0; float l1 = acc[0];
      #pragma unroll
      for (int e = 1; e < E_NUM; e++) { if (acc[e] > l1) { l1 = acc[e]; e1 = e; } }
      int e2 = -1; float l2 = -1e30f;
      #pragma unroll
      for (int e = 0; e < E_NUM; e++) { if (e != e1 && acc[e] > l2) { l2 = acc[e]; e2 = e; } }
      float wa = 1.f / (1.f + expf(l2 - l1));
      float wb = 1.f / (1.f + expf(l1 - l2));
      route_e[t] = e1 | (e2 << 8);
      route_w[t] = make_float2(wa, wb);
    }
  }
}

// ---------------- scatter: deterministic prefix-sum compaction + tiles, 1 block ----------
__global__ __launch_bounds__(1024) void scatter_kernel(
    const int* __restrict__ route_e, const float2* __restrict__ route_w,
    int* __restrict__ counts, int4* __restrict__ tiles,
    int* __restrict__ list, float* __restrict__ wts) {
  int tid = threadIdx.x;
  int lane = tid & 63, wv = tid >> 6;
  __shared__ int wave_tot[16][E_NUM];
  __shared__ int wave_base[16][E_NUM];
  __shared__ int tot_s[E_NUM];

  int e_loc[8]; float w_loc[8];
  #pragma unroll
  for (int j = 0; j < 4; j++) {
    int t = tid * 4 + j;
    int re = route_e[t];
    float2 rw = route_w[t];
    e_loc[2 * j]     = re & 0xff; w_loc[2 * j]     = rw.x;
    e_loc[2 * j + 1] = re >> 8;   w_loc[2 * j + 1] = rw.y;
  }
  int c[E_NUM], pre[E_NUM];
  #pragma unroll
  for (int e = 0; e < E_NUM; e++) {
    int s = 0;
    #pragma unroll
    for (int j = 0; j < 8; j++) s += (e_loc[j] == e) ? 1 : 0;
    c[e] = s;
  }
  #pragma unroll
  for (int e = 0; e < E_NUM; e++) {
    int v = c[e];
    #pragma unroll
    for (int off = 1; off < 64; off <<= 1) {
      int u = __shfl_up(v, off);
      if (lane >= off) v += u;
    }
    pre[e] = v - c[e];
    if (lane == 63) wave_tot[wv][e] = v;
  }
  __syncthreads();
  if (tid < E_NUM) {
    int s = 0;
    for (int w = 0; w < 16; w++) { wave_base[w][tid] = s; s += wave_tot[w][tid]; }
    tot_s[tid] = s;
    counts[tid] = s;
  }
  __syncthreads();
  #pragma unroll
  for (int j = 0; j < 8; j++) {
    int e = e_loc[j];
    int off = 0;
    #pragma unroll
    for (int jj = 0; jj < 8; jj++)
      if (jj < j) off += (e_loc[jj] == e) ? 1 : 0;
    int basee = 0, pree = 0;
    #pragma unroll
    for (int ee = 0; ee < E_NUM; ee++)
      if (e == ee) { basee = wave_base[wv][ee]; pree = pre[ee]; }
    int pos = basee + pree + off;
    int t = tid * 4 + (j >> 1);
    list[e * T_TOK + pos] = t * 2 + (j & 1);
    wts[e * T_TOK + pos]  = w_loc[j];
  }
  // tile descriptors (64-row granularity)
  if (tid < MAX_TILES) {
    int4 tt; tt.x = -1; tt.y = 0; tt.z = 0; tt.w = 0;
    int s = 0;
    #pragma unroll
    for (int e = 0; e < E_NUM; e++) {
      int ntl = (tot_s[e] + 63) >> 6;
      if (tid >= s && tid < s + ntl) { tt.x = e; tt.y = (tid - s) * 64; tt.z = tot_s[e]; }
      s += ntl;
    }
    tiles[tid] = tt;
  }
}

// ---------------- GEMM1 (+ fused w2 transpose in leading y-slices) ----------------
// y < TZ: transpose w2 [F][D]->[D][F] (512 blocks x 8 experts each)
// y >= TZ: R9-form 64x64 dual-branch GEMM tile
__global__ __launch_bounds__(256, 4) void gemm1_kernel(
    const us* __restrict__ Xb,   // [T][D] bf16
    const us* __restrict__ W1t,  // [E][F][D] bf16
    const us* __restrict__ W3t,  // [E][F][D] bf16
    const int4* __restrict__ tiles, const int* __restrict__ list,
    us* __restrict__ H,          // [T*2][F] bf16
    const float* __restrict__ w2, us* __restrict__ W2t) {
  __shared__ __align__(16) us smem[3 * 64 * 64];   // 24 KB, aliased by both paths
  __shared__ int rid_s[64];
  int tid = threadIdx.x;

  if (blockIdx.y < TZ) {
    // ---- w2 transpose+convert path ----
    float (*tile)[65] = (float(*)[65])smem;        // 16.6 KB <= 24 KB
    int slot = blockIdx.y * 32 + blockIdx.x;       // 0..511: within-expert tile id
    int i0 = (slot >> 4) * 64;                     // F-dim (32 tiles)
    int j0 = (slot & 15) * 64;                     // D-dim (16 tiles)
    int lr = tid >> 4, lc = (tid & 15) * 4;
    #pragma unroll 1
    for (int e = 0; e < E_NUM; e++) {
      const float* src = w2 + (size_t)e * F_DIM * D_DIM;
      us* dst = W2t + (size_t)e * F_DIM * D_DIM;
      #pragma unroll
      for (int p = 0; p < 4; p++) {
        int row = p * 16 + lr;
        float4 v = *(const float4*)&src[(size_t)(i0 + row) * D_DIM + j0 + lc];
        tile[row][lc + 0] = v.x; tile[row][lc + 1] = v.y;
        tile[row][lc + 2] = v.z; tile[row][lc + 3] = v.w;
      }
      __syncthreads();
      #pragma unroll
      for (int p = 0; p < 4; p++) {
        int orow = p * 16 + lr;                    // D-index
        us b0 = f2bf(tile[lc + 0][orow]);
        us b1 = f2bf(tile[lc + 1][orow]);
        us b2 = f2bf(tile[lc + 2][orow]);
        us b3 = f2bf(tile[lc + 3][orow]);
        uint2 o;
        o.x = b0 | ((unsigned)b1 << 16);
        o.y = b2 | ((unsigned)b3 << 16);
        *(uint2*)&dst[(size_t)(j0 + orow) * F_DIM + i0 + lc] = o;
      }
      __syncthreads();
    }
    return;
  }

  // ---- GEMM path (R9 form) ----
  us* As  = smem;
  us* B1s = smem + 4096;
  us* B3s = smem + 8192;

  int4 td = tiles[blockIdx.y - TZ];
  int e = td.x;
  if (e < 0) return;
  int base = td.y, cnt = td.z;
  int nt = blockIdx.x;          // 0..31 over F/64

  if (tid < 64) {
    int r = base + tid; if (r > cnt - 1) r = cnt - 1;
    rid_s[tid] = list[e * T_TOK + r];
  }
  __syncthreads();

  int lane = tid & 63, wid = tid >> 6;       // wid 0..3
  int sr = lane >> 3;                        // 0..7
  int sg = (lane & 7) ^ sr;                  // pre-swizzled source granule
  const us* a_src[2];
  #pragma unroll
  for (int t = 0; t < 2; t++)
    a_src[t] = Xb + (size_t)(rid_s[wid * 16 + t * 8 + sr] >> 1) * D_DIM + sg * 8;
  const us *b1_src[2], *b3_src[2];
  #pragma unroll
  for (int t = 0; t < 2; t++) {
    size_t row = (size_t)e * F_DIM + nt * 64 + wid * 16 + t * 8 + sr;
    b1_src[t] = W1t + row * D_DIM + sg * 8;
    b3_src[t] = W3t + row * D_DIM + sg * 8;
  }

  int wm = (wid >> 1) * 32, wn = (wid & 1) * 32;
  int frow = lane & 15;
  int fk = lane >> 4;

  unsigned offA[2][2], offB[2][2];
  #pragma unroll
  for (int mf = 0; mf < 2; mf++)
    #pragma unroll
    for (int kc = 0; kc < 2; kc++) {
      int m = wm + mf * 16 + frow, gk = kc * 4 + fk;
      offA[mf][kc] = m * 64 + ((gk ^ (m & 7)) * 8);
    }
  #pragma unroll
  for (int nf = 0; nf < 2; nf++)
    #pragma unroll
    for (int kc = 0; kc < 2; kc++) {
      int n = wn + nf * 16 + frow, gk = kc * 4 + fk;
      offB[nf][kc] = n * 64 + ((gk ^ (n & 7)) * 8);
    }

  f32x4 acc1[2][2], acc3[2][2];
  #pragma unroll
  for (int mf = 0; mf < 2; mf++)
    #pragma unroll
    for (int nf = 0; nf < 2; nf++) {
      f32x4 z = {0.f, 0.f, 0.f, 0.f};
      acc1[mf][nf] = z; acc3[mf][nf] = z;
    }

  #pragma unroll 1
  for (int k0 = 0; k0 < D_DIM; k0 += 64) {
    #pragma unroll
    for (int t = 0; t < 2; t++) {
      gload16(a_src[t] + k0, &As[(wid * 16 + t * 8) * 64]);
      gload16(b1_src[t] + k0, &B1s[(wid * 16 + t * 8) * 64]);
      gload16(b3_src[t] + k0, &B3s[(wid * 16 + t * 8) * 64]);
    }
    __syncthreads();
    #pragma unroll
    for (int kc = 0; kc < 2; kc++) {
      bf16x8 a[2], b1[2], b3[2];
      #pragma unroll
      for (int mf = 0; mf < 2; mf++) a[mf] = *(const bf16x8*)&As[offA[mf][kc]];
      #pragma unroll
      for (int nf = 0; nf < 2; nf++) {
        b1[nf] = *(const bf16x8*)&B1s[offB[nf][kc]];
        b3[nf] = *(const bf16x8*)&B3s[offB[nf][kc]];
      }
      #pragma unroll
      for (int mf = 0; mf < 2; mf++)
        #pragma unroll
        for (int nf = 0; nf < 2; nf++) {
          acc1[mf][nf] = mfma16(a[mf], b1[nf], acc1[mf][nf]);
          acc3[mf][nf] = mfma16(a[mf], b3[nf], acc3[mf][nf]);
        }
    }
    __syncthreads();
  }

  #pragma unroll
  for (int mf = 0; mf < 2; mf++) {
    #pragma unroll
    for (int i = 0; i < 4; i++) {
      int m = wm + mf * 16 + fk * 4 + i;
      if (base + m < cnt) {
        int rid = rid_s[m];
        us* hrow = H + (size_t)rid * F_DIM + nt * 64 + wn;
        #pragma unroll
        for (int nf = 0; nf < 2; nf++) {
          float z = acc1[mf][nf][i];
          float u = acc3[mf][nf][i];
          hrow[nf * 16 + frow] = f2bf((z / (1.f + expf(-z))) * u);
        }
      }
    }
  }
}

// ---------------- GEMM2: out += (H @ w2) * weight, 64x128 tile, 4 waves ------------------
__global__ __launch_bounds__(256, 4) void gemm2_kernel(
    const us* __restrict__ H,    // [T*2][F] bf16
    const us* __restrict__ W2t,  // [E][D][F] bf16
    const int4* __restrict__ tiles, const int* __restrict__ list,
    const float* __restrict__ wts,
    float* __restrict__ out) {   // [T][D] fp32 (pre-zeroed)
  __shared__ us As[64 * 64];     // 8 KB
  __shared__ us Bs[128 * 64];    // 16 KB
  __shared__ int rid_s[64];
  __shared__ float wt_s[64];

  int4 td = tiles[blockIdx.y];
  int e = td.x;
  if (e < 0) return;
  int base = td.y, cnt = td.z;
  int nt = blockIdx.x;   // 0..7 over D/128
  int tid = threadIdx.x;

  if (tid < 64) {
    int r = base + tid; if (r > cnt - 1) r = cnt - 1;
    rid_s[tid] = list[e * T_TOK + r];
    wt_s[tid] = wts[e * T_TOK + r];
  }
  __syncthreads();

  int lane = tid & 63, wid = tid >> 6;
  int sr = lane >> 3;
  int sg = (lane & 7) ^ sr;
  const us* a_src[2];
  #pragma unroll
  for (int t = 0; t < 2; t++)
    a_src[t] = H + (size_t)rid_s[wid * 16 + t * 8 + sr] * F_DIM + sg * 8;
  const us* b_src[4];
  #pragma unroll
  for (int t = 0; t < 4; t++)
    b_src[t] = W2t + ((size_t)e * D_DIM + nt * 128 + wid * 32 + t * 8 + sr) * F_DIM + sg * 8;

  int wm = (wid >> 1) * 32, wn = (wid & 1) * 64;
  int frow = lane & 15;
  int fk = lane >> 4;

  unsigned offA[2][2], offB[4][2];
  #pragma unroll
  for (int mf = 0; mf < 2; mf++)
    #pragma unroll
    for (int kc = 0; kc < 2; kc++) {
      int m = wm + mf * 16 + frow, gk = kc * 4 + fk;
      offA[mf][kc] = m * 64 + ((gk ^ (m & 7)) * 8);
    }
  #pragma unroll
  for (int nf = 0; nf < 4; nf++)
    #pragma unroll
    for (int kc = 0; kc < 2; kc++) {
      int n = wn + nf * 16 + frow, gk = kc * 4 + fk;
      offB[nf][kc] = n * 64 + ((gk ^ (n & 7)) * 8);
    }

  f32x4 acc[2][4];
  #pragma unroll
  for (int mf = 0; mf < 2; mf++)
    #pragma unroll
    for (int nf = 0; nf < 4; nf++) {
      f32x4 z = {0.f, 0.f, 0.f, 0.f};
      acc[mf][nf] = z;
    }

  #pragma unroll 1
  for (int k0 = 0; k0 < F_DIM; k0 += 64) {
    #pragma unroll
    for (int t = 0; t < 2; t++)
      gload16(a_src[t] + k0, &As[(wid * 16 + t * 8) * 64]);
    #pragma unroll
    for (int t = 0; t < 4; t++)
      gload16(b_src[t] + k0, &Bs[(wid * 32 + t * 8) * 64]);
    __syncthreads();
    #pragma unroll
    for (int kc = 0; kc < 2; kc++) {
      bf16x8 a[2], b[4];
      #pragma unroll
      for (int mf = 0; mf < 2; mf++) a[mf] = *(const bf16x8*)&As[offA[mf][kc]];
      #pragma unroll
      for (int nf = 0; nf < 4; nf++) b[nf] = *(const bf16x8*)&Bs[offB[nf][kc]];
      #pragma unroll
      for (int mf = 0; mf < 2; mf++)
        #pragma unroll
        for (int nf = 0; nf < 4; nf++)
          acc[mf][nf] = mfma16(a[mf], b[nf], acc[mf][nf]);
    }
    __syncthreads();
  }

  #pragma unroll
  for (int mf = 0; mf < 2; mf++) {
    #pragma unroll
    for (int i = 0; i < 4; i++) {
      int m = wm + mf * 16 + fk * 4 + i;
      if (base + m < cnt) {
        int tok = rid_s[m] >> 1;
        float w = wt_s[m];
        float* orow = out + (size_t)tok * D_DIM + nt * 128 + wn;
        #pragma unroll
        for (int nf = 0; nf < 4; nf++)
          atomicAdd(&orow[nf * 16 + frow], acc[mf][nf][i] * w);
      }
    }
  }
}

extern "C" void kernel_launch(void* const* d_in, const int* in_sizes, int n_in,
                              void* d_out, int out_size, void* d_ws, size_t ws_size,
                              hipStream_t stream) {
  const float* x  = (const float*)d_in[0];
  const float* gw = (const float*)d_in[1];
  const float* w1 = (const float*)d_in[2];
  const float* w2 = (const float*)d_in[3];
  const float* w3 = (const float*)d_in[4];
  float* out = (float*)d_out;

  char* ws = (char*)d_ws;
  const size_t LISTB = (size_t)E_NUM * T_TOK * 4;
  size_t o_counts  = 0;
  size_t o_tiles   = 256;                                   // int4[136]
  size_t o_route_e = 4096;
  size_t o_route_w = o_route_e + (size_t)T_TOK * 4;
  size_t o_list    = o_route_w + (size_t)T_TOK * 8;
  size_t o_wts     = o_list + LISTB;
  size_t o_Xb      = o_wts + LISTB;
  size_t o_W1t     = o_Xb + (size_t)T_TOK * D_DIM * 2;
  size_t wt_sz     = (size_t)E_NUM * F_DIM * D_DIM * 2;
  size_t o_W3t     = o_W1t + wt_sz;
  size_t o_W2t     = o_W3t + wt_sz;
  size_t o_H       = o_W2t + wt_sz;

  int* counts    = (int*)(ws + o_counts);
  int4* tiles    = (int4*)(ws + o_tiles);
  int* route_e   = (int*)(ws + o_route_e);
  float2* route_w = (float2*)(ws + o_route_w);
  int* list      = (int*)(ws + o_list);
  float* wts     = (float*)(ws + o_wts);
  us* Xb  = (us*)(ws + o_Xb);
  us* W1t = (us*)(ws + o_W1t);
  us* W3t = (us*)(ws + o_W3t);
  us* W2t = (us*)(ws + o_W2t);
  us* H   = (us*)(ws + o_H);

  hipMemsetAsync(out, 0, (size_t)out_size * 4, stream);

  // z<16: w1/w3 transpose; z=16..17: router logits (co-resident)
  prep_kernel<<<dim3(32, 16, 18), 256, 0, stream>>>(
      w1, w3, W1t, W3t, x, gw, route_e, route_w, Xb);

  scatter_kernel<<<dim3(1), 1024, 0, stream>>>(route_e, route_w, counts,
                                               tiles, list, wts);

  // y<TZ: w2 transpose (hidden under gemm compute); y>=TZ: gemm tiles
  gemm1_kernel<<<dim3(F_DIM / 64, TZ + MAX_TILES), 256, 0, stream>>>(
      Xb, W1t, W3t, tiles, list, H, w2, W2t);
  gemm2_kernel<<<dim3(D_DIM / 128, MAX_TILES), 256, 0, stream>>>(
      H, W2t, tiles, list, wts, out);
}